// Round 19
// baseline (26.069 us; speedup 1.0000x reference)
//
#include <hip/hip_runtime.h>

#define D 64
#define L 10
#define C 256
#define GPB 4   // users per group
#define SWB 72  // bf16 LDS row stride in shorts (144 B, 16B-aligned)
#define ST 66   // s2 row stride in float2 (528 B)

typedef __attribute__((ext_vector_type(8))) short bf16x8;
typedef __attribute__((ext_vector_type(4))) short short4v;
typedef __attribute__((ext_vector_type(4))) float f32x4;

__device__ inline short f2bf(float f) {
  unsigned u = __float_as_uint(f);
  u = (u + 0x7FFFu + ((u >> 16) & 1u)) >> 16;
  return (short)u;
}
__device__ inline float4 add3(float4 a, float4 b, float4 c) {
  return make_float4(a.x + b.x + c.x, a.y + b.y + c.y, a.z + b.z + c.z, a.w + b.w + c.w);
}
__device__ inline short4v f2bf4(float4 a) {
  short4v r;
  r[0] = f2bf(a.x); r[1] = f2bf(a.y); r[2] = f2bf(a.z); r[3] = f2bf(a.w);
  return r;
}

// Coalesced pre (verified R8). Bf[c][k] = bf16(0.125*(cl@Wk@Wq^T)[c][k]),
// Bf[c][64+d] = bf16((cl@Wv)[c][d]).
__global__ __launch_bounds__(256) void pre(const float* __restrict__ cl,
                                           const float* __restrict__ Wk,
                                           const float* __restrict__ Wq,
                                           const float* __restrict__ Wv,
                                           short* __restrict__ Bf) {
  __shared__ float s_cl[4 * 64];
  __shared__ float s_kc[4 * 64];
  __shared__ float s_w[64 * 65];
  const int t = threadIdx.x;
  const int bh = blockIdx.x >> 6, cb = blockIdx.x & 63;
  const int c0 = cb * 4;
  const int r = t >> 6, j = t & 63;

  s_cl[t] = cl[c0 * 64 + t];
  if (bh == 0) {
#pragma unroll
    for (int i = 0; i < 4; ++i) {
      int e = i * 256 + t;
      float4 v = ((const float4*)Wq)[e];
      int k = e >> 4, q = e & 15;
      float* dst = &s_w[k * 65 + q * 4];
      dst[0] = v.x; dst[1] = v.y; dst[2] = v.z; dst[3] = v.w;
    }
  }
  __syncthreads();

  const float* __restrict__ Wx = bh ? Wv : Wk;
  float acc = 0.f;
#pragma unroll 8
  for (int m = 0; m < 64; ++m) acc += s_cl[r * 64 + m] * Wx[m * 64 + j];

  if (bh == 1) {
    Bf[(c0 + r) * 128 + 64 + j] = f2bf(acc);
    return;
  }
  s_kc[t] = acc;
  __syncthreads();

  float o = 0.f;
#pragma unroll 8
  for (int jj = 0; jj < 64; ++jj) o += s_kc[r * 64 + jj] * s_w[j * 65 + jj];
  Bf[(c0 + r) * 128 + j] = f2bf(0.125f * o);
}

// Sum one s2 row (64 float2 partials) across 4 chunk-lanes.
__device__ inline float reduce_row(const float2* __restrict__ rowp, int chunk) {
  float sx = 0.f, sy = 0.f;
#pragma unroll
  for (int j = 0; j < 8; ++j) {
    int jr = (j + chunk) & 7;
    float4 v = *(const float4*)&rowp[chunk * 16 + jr * 2];
    sx += v.x + v.z;
    sy += v.y + v.w;
  }
  sx += __shfl_xor(sx, 1, 64);
  sy += __shfl_xor(sy, 1, 64);
  sx += __shfl_xor(sx, 2, 64);
  sy += __shfl_xor(sy, 2, 64);
  return sy * __frcp_rn(sx);  // s_l = T/S, valid in chunk==0 lanes
}

__device__ inline float bcast(float v, int srclane) {
  return __uint_as_float(__builtin_amdgcn_readlane(__float_as_uint(v), srclane));
}

// R19: 2-group pipelined filter. Each block handles user-groups bid and
// bid+NG (G=4 each). Zero-shuffle packing (exact at G=4): M-row m ->
// user m>>2, l = mt*4 + (m&3). A-load: g=qr, l=mt*4+jr (zero if l>=10);
// C/D: g=kb, l=mt*4+jj; ue tile duplicated 4x -> vu = own cu[0].
__global__ __launch_bounds__(256) void filter_main(
    const int* __restrict__ items, const float* __restrict__ te,
    const float* __restrict__ ue_g, const float* __restrict__ ie_g,
    const float* __restrict__ wf_g, const short* __restrict__ Bf,
    const int* __restrict__ users, const int* __restrict__ pos_items,
    const int* __restrict__ neg_items, const float* __restrict__ a1p,
    const float* __restrict__ a2p, const float* __restrict__ a3p,
    float* __restrict__ out, int B, int NG) {
  __shared__ short s_shb[2][44 * SWB];  // per-group: 40 short + 4 ue rows
  __shared__ float2 s2[40 * ST];        // (S,T) partials, reused per group

  const int tid = threadIdx.x, w = tid >> 6, lane = tid & 63;
  const int col16 = lane & 15, kb = lane >> 4;
  const int qr = col16 >> 2, jr = col16 & 3;
  const int BD = B * D;

  const int base0 = blockIdx.x * GPB;          // group 0 user base
  const int base1 = (blockIdx.x + NG) * GPB;   // group 1 user base

  // ---- staging macro: gather group rows -> bf16 LDS buf
#define STAGE(BUF, B4)                                                         \
  {                                                                            \
    const float4* te4 = (const float4*)te;                                     \
    const float4* ie4 = (const float4*)ie_g;                                   \
    const float4* ue4 = (const float4*)ue_g;                                   \
    const int grp = tid >> 4, j = tid & 15;                                    \
    _Pragma("unroll") for (int it = 0; it < 3; ++it) {                         \
      int row = it * 16 + grp;                                                 \
      if (row < 40) {                                                          \
        int g = row / 10, l = row - g * 10;                                    \
        int u = users[(B4) + g];                                               \
        int itm = items[u * L + l];                                            \
        float4 v = add3(te4[(u * L + l) * 16 + j], ie4[itm * 16 + j],          \
                        ue4[u * 16 + j]);                                      \
        *(short4v*)&(BUF)[row * SWB + j * 4] = f2bf4(v);                       \
      } else if (row < 44) {                                                   \
        int u = users[(B4) + (row - 40)];                                      \
        *(short4v*)&(BUF)[row * SWB + j * 4] = f2bf4(ue4[u * 16 + j]);         \
      }                                                                        \
    }                                                                          \
  }

  // ---- A-fragment load macro (from a staged buf)
#define AFRAG(BUF, AF, AU0, AU1)                                               \
  {                                                                            \
    _Pragma("unroll") for (int mt = 0; mt < 3; ++mt) {                         \
      int l = mt * 4 + jr;                                                     \
      if (l < L) {                                                             \
        const bf16x8* rp = (const bf16x8*)&(BUF)[(qr * 10 + l) * SWB];         \
        AF[mt][0] = rp[kb];                                                    \
        AF[mt][1] = rp[4 + kb];                                                \
      } else {                                                                 \
        AF[mt][0] = bf16x8{};                                                  \
        AF[mt][1] = bf16x8{};                                                  \
      }                                                                        \
    }                                                                          \
    const bf16x8* rp = (const bf16x8*)&(BUF)[(40 + qr) * SWB];                 \
    AU0 = rp[kb];                                                              \
    AU1 = rp[4 + kb];                                                          \
  }

  // ---- compute macro: MFMA + exp accumulate into Sa/Ta
#define COMPUTE(AF, AU0, AU1, SA, TA)                                          \
  {                                                                            \
    _Pragma("unroll") for (int mt = 0; mt < 3; ++mt)                           \
        _Pragma("unroll") for (int jj = 0; jj < 4; ++jj) {                     \
      SA[mt][jj] = 0.f;                                                        \
      TA[mt][jj] = 0.f;                                                        \
    }                                                                          \
    _Pragma("unroll") for (int nt = 0; nt < 4; ++nt) {                         \
      const bf16x8* bp =                                                       \
          (const bf16x8*)(Bf + ((w * 4 + nt) * 16 + col16) * 128);             \
      bf16x8 b0 = bp[kb], b1 = bp[4 + kb], b2 = bp[8 + kb], b3 = bp[12 + kb];  \
      f32x4 z = {0.f, 0.f, 0.f, 0.f};                                          \
      f32x4 cc[3];                                                             \
      f32x4 cu = z;                                                            \
      _Pragma("unroll") for (int mt = 0; mt < 3; ++mt) {                       \
        cc[mt] = z;                                                            \
        cc[mt] = __builtin_amdgcn_mfma_f32_16x16x32_bf16(AF[mt][0], b0,        \
                                                         cc[mt], 0, 0, 0);     \
        cc[mt] = __builtin_amdgcn_mfma_f32_16x16x32_bf16(AF[mt][1], b1,        \
                                                         cc[mt], 0, 0, 0);     \
      }                                                                        \
      cu = __builtin_amdgcn_mfma_f32_16x16x32_bf16(AU0, b2, cu, 0, 0, 0);      \
      cu = __builtin_amdgcn_mfma_f32_16x16x32_bf16(AU1, b3, cu, 0, 0, 0);      \
      const float vuv = cu[0]; /* user kb for every score this lane owns */    \
      _Pragma("unroll") for (int mt = 0; mt < 3; ++mt)                         \
          _Pragma("unroll") for (int jj = 0; jj < 4; ++jj) {                   \
        if (mt * 4 + jj < L) {                                                 \
          float e = __expf(cc[mt][jj]);                                        \
          SA[mt][jj] += e;                                                     \
          TA[mt][jj] += e * vuv;                                               \
        }                                                                      \
      }                                                                        \
    }                                                                          \
  }

  // ================= group 0: stage =================
  STAGE(s_shb[0], base0)
  // hoisted per-user loads, group 0 (wave w owns user w)
  const int u0 = users[base0 + w];
  const float uev0 = ue_g[u0 * D + lane];
  const float posv0 = ie_g[pos_items[base0 + w] * D + lane];
  const float negv0 = ie_g[neg_items[base0 + w] * D + lane];
  float wfv0[L];
#pragma unroll
  for (int l = 0; l < L; ++l) wfv0[l] = wf_g[(u0 * L + l) * D + lane];
  __syncthreads();

  // A-frags(0), then immediately issue group-1 gathers (drain under compute)
  bf16x8 af0[3][2], au00, au01;
  AFRAG(s_shb[0], af0, au00, au01)
  STAGE(s_shb[1], base1)
  const int u1 = users[base1 + w];
  const float uev1 = ue_g[u1 * D + lane];
  const float posv1 = ie_g[pos_items[base1 + w] * D + lane];
  const float negv1 = ie_g[neg_items[base1 + w] * D + lane];
  float wfv1[L];
#pragma unroll
  for (int l = 0; l < L; ++l) wfv1[l] = wf_g[(u1 * L + l) * D + lane];

  // ---- compute(0)
  float Sa[3][4], Ta[3][4];
  COMPUTE(af0, au00, au01, Sa, Ta)

  // s2 write(0): row = kb*10 + (mt*4+jj), col w*16+col16
#pragma unroll
  for (int mt = 0; mt < 3; ++mt)
#pragma unroll
    for (int jj = 0; jj < 4; ++jj) {
      const int l = mt * 4 + jj;
      if (l < L)
        s2[(kb * 10 + l) * ST + w * 16 + col16] =
            make_float2(Sa[mt][jj], Ta[mt][jj]);
    }
  __syncthreads();

  // reduce + epilogue(0): wave w owns user w
  {
    const int slot = lane >> 2, chunk = lane & 3;
    int rowA = w * 10 + ((slot < 10) ? slot : 0);
    float slv = reduce_row(&s2[rowA * ST], chunk);
    float nu = 0.f;
#pragma unroll
    for (int l = 0; l < L; ++l) nu += bcast(slv, l * 4) * wfv0[l];
    const float a1 = *a1p, a2 = *a2p, a3 = *a3p;
    out[(base0 + w) * D + lane] = a3 * (a1 * uev0 + a2 * nu);
    out[BD + (base0 + w) * D + lane] = posv0;
    out[2 * BD + (base0 + w) * D + lane] = negv0;
  }
  __syncthreads();  // s2 reads done; buf1 staging writes done

  // ================= group 1 =================
  bf16x8 af1[3][2], au10, au11;
  AFRAG(s_shb[1], af1, au10, au11)
  COMPUTE(af1, au10, au11, Sa, Ta)

#pragma unroll
  for (int mt = 0; mt < 3; ++mt)
#pragma unroll
    for (int jj = 0; jj < 4; ++jj) {
      const int l = mt * 4 + jj;
      if (l < L)
        s2[(kb * 10 + l) * ST + w * 16 + col16] =
            make_float2(Sa[mt][jj], Ta[mt][jj]);
    }
  __syncthreads();

  {
    const int slot = lane >> 2, chunk = lane & 3;
    int rowA = w * 10 + ((slot < 10) ? slot : 0);
    float slv = reduce_row(&s2[rowA * ST], chunk);
    float nu = 0.f;
#pragma unroll
    for (int l = 0; l < L; ++l) nu += bcast(slv, l * 4) * wfv1[l];
    const float a1 = *a1p, a2 = *a2p, a3 = *a3p;
    out[(base1 + w) * D + lane] = a3 * (a1 * uev1 + a2 * nu);
    out[BD + (base1 + w) * D + lane] = posv1;
    out[2 * BD + (base1 + w) * D + lane] = negv1;
  }
}

extern "C" void kernel_launch(void* const* d_in, const int* in_sizes, int n_in,
                              void* d_out, int out_size, void* d_ws, size_t ws_size,
                              hipStream_t stream) {
  const int* items = (const int*)d_in[0];
  const float* time_embs = (const float*)d_in[1];
  const float* user_emb = (const float*)d_in[2];
  const float* item_emb = (const float*)d_in[3];
  const float* cluster = (const float*)d_in[4];
  const float* wf = (const float*)d_in[5];
  const float* Wq = (const float*)d_in[6];
  const float* Wk = (const float*)d_in[7];
  const float* Wv = (const float*)d_in[8];
  const int* users = (const int*)d_in[9];
  const int* pos = (const int*)d_in[10];
  const int* neg = (const int*)d_in[11];
  const float* a1 = (const float*)d_in[12];
  const float* a2 = (const float*)d_in[13];
  const float* a3 = (const float*)d_in[14];
  const int B = in_sizes[9];
  const int NG = B / GPB / 2;  // blocks; each does groups bid and bid+NG

  short* Bf = (short*)d_ws;  // [C][128] bf16
  hipLaunchKernelGGL(pre, dim3(128), dim3(256), 0, stream,
                     cluster, Wk, Wq, Wv, Bf);
  hipLaunchKernelGGL(filter_main, dim3(NG), dim3(256), 0, stream,
                     items, time_embs, user_emb, item_emb, wf, Bf,
                     users, pos, neg, a1, a2, a3, (float*)d_out, B, NG);
}